// Round 1
// baseline (452.324 us; speedup 1.0000x reference)
//
#include <hip/hip_runtime.h>
#include <hip/hip_bf16.h>

// Problem constants (fixed by reference setup_inputs).
#define T_TOTAL 2048
#define BATCH   128
#define NIN     256
#define NOUT    128

// Decomposition: T-chunks x B-chunks. Warm-up recomputes trace history.
#define TC      256                 // timesteps per block
#define BC      4                   // batches per block
#define WARM    32                  // warm-up steps (0.5^32 ~ 2e-10 truncation)
#define G       4                   // timesteps per MFMA K-group (K = G*BC = 16)
#define NTC     (T_TOTAL / TC)      // 8
#define NBC     (BATCH / BC)        // 32
#define NBLOCKS (NTC * NBC)         // 256
#define NG      (TC / G)            // 64 K-groups per block

#define ROWU      24                // ushorts per LDS row: 16 data + 8 pad = 48 B (16B-aligned, bank-tiling)
#define OUT_ELEMS (NOUT * NIN)      // 32768

typedef __attribute__((ext_vector_type(8)))  __bf16 bf16x8;
typedef __attribute__((ext_vector_type(16))) float  f32x16;

static __device__ __forceinline__ unsigned short f2bf(float x) {
    union { float f; unsigned u; } v; v.f = x;
    unsigned r = v.u + 0x7FFFu + ((v.u >> 16) & 1u);   // RTNE
    return (unsigned short)(r >> 16);
}

// Main fused kernel: trace scan (fp32 registers) + bf16 MFMA accumulation.
// dst: either ws partial slots (use_atomic=0: slot=blockIdx, plain store)
//      or shared slots / d_out (use_atomic=1: slot=blockIdx%nslots, atomicAdd).
__global__ __launch_bounds__(512, 2)
void stdp_main(const float* __restrict__ in, const float* __restrict__ outs,
               float* __restrict__ dst, int nslots, int use_atomic)
{
    __shared__ unsigned short tr_lds[2][NIN * ROWU];   // 2 x 12 KB, B operand (trace, n=i)
    __shared__ unsigned short ot_lds[2][NOUT * ROWU];  // 2 x  6 KB, A operand (out-spikes, m=o)

    const int tid = threadIdx.x;
    const int bc  = blockIdx.x % NBC;
    const int tc  = blockIdx.x / NBC;
    const int b0  = bc * BC;
    const int t0  = tc * TC;

    // trace ownership: thread -> (i = tid&255, batches b0+2*bh, b0+2*bh+1)
    const int i_idx = tid & 255;
    const int bh    = tid >> 8;          // 0/1
    // out staging ownership: thread -> (o = tid&127, b_local = (tid>>7)&3)
    const int o_idx = tid & 127;
    const int blo   = (tid >> 7) & 3;

    float tr0 = 0.f, tr1 = 0.f;

    // ---- warm-up: trace scan only (no MFMA), batched loads ----
    if (tc > 0) {
        for (int t = t0 - WARM; t < t0; t += 8) {
            float v0[8], v1[8];
#pragma unroll
            for (int u = 0; u < 8; ++u) {
                const size_t base = ((size_t)(t + u) * BATCH + b0 + 2 * bh) * NIN + i_idx;
                v0[u] = in[base];
                v1[u] = in[base + NIN];
            }
#pragma unroll
            for (int u = 0; u < 8; ++u) {
                tr0 = 0.5f * tr0 + v0[u];
                tr1 = 0.5f * tr1 + v1[u];
            }
        }
    }

    f32x16 acc[4];
#pragma unroll
    for (int j = 0; j < 4; ++j) acc[j] = (f32x16)(0.f);

    // ---- preload group 0 ----
    float pin0[G], pin1[G], pout[G];
#pragma unroll
    for (int q = 0; q < G; ++q) {
        const size_t baseI = ((size_t)(t0 + q) * BATCH + b0 + 2 * bh) * NIN + i_idx;
        pin0[q] = in[baseI];
        pin1[q] = in[baseI + NIN];
        pout[q] = outs[((size_t)(t0 + q) * BATCH + b0 + blo) * NOUT + o_idx];
    }

    const int lane  = tid & 63;
    const int wv    = tid >> 6;          // 8 waves
    const int mt    = wv & 3;            // m-tile (NOUT rows mt*32..+31)
    const int ntb   = (wv >> 2) * 4;     // n-tile base (4 tiles per wave)
    const int l31   = lane & 31;
    const int khalf = lane >> 5;         // 0/1 -> k offset 0/8

    for (int g = 0; g < NG; ++g) {
        // prefetch next group's globals (fly under this group's compute)
        float nin0[G], nin1[G], nout_[G];
        if (g + 1 < NG) {
            const int tg = t0 + (g + 1) * G;
#pragma unroll
            for (int q = 0; q < G; ++q) {
                const size_t baseI = ((size_t)(tg + q) * BATCH + b0 + 2 * bh) * NIN + i_idx;
                nin0[q]  = in[baseI];
                nin1[q]  = in[baseI + NIN];
                nout_[q] = outs[((size_t)(tg + q) * BATCH + b0 + blo) * NOUT + o_idx];
            }
        }

        // trace recurrence (exact fp32), pack to bf16 pairs. k = tl*4 + b_local
        unsigned words[G];
#pragma unroll
        for (int q = 0; q < G; ++q) {
            tr0 = 0.5f * tr0 + pin0[q];
            tr1 = 0.5f * tr1 + pin1[q];
            words[q] = (unsigned)f2bf(tr0) | ((unsigned)f2bf(tr1) << 16);
        }

        const int buf = g & 1;
        // B operand rows: trace_lds[i][k], thread writes its k pair per tl
        unsigned* trow = (unsigned*)&tr_lds[buf][i_idx * ROWU];
#pragma unroll
        for (int q = 0; q < G; ++q) trow[q * 2 + bh] = words[q];
        // A operand rows: ot_lds[o][k]
        unsigned short* orow = &ot_lds[buf][o_idx * ROWU];
#pragma unroll
        for (int q = 0; q < G; ++q) orow[q * 4 + blo] = f2bf(pout[q]);

        __syncthreads();   // single barrier per group (double-buffered LDS)

        // A frag: A[m = l31][k = khalf*8 + j]
        const bf16x8 a = *(const bf16x8*)&ot_lds[buf][(mt * 32 + l31) * ROWU + khalf * 8];
#pragma unroll
        for (int j = 0; j < 4; ++j) {
            const bf16x8 b = *(const bf16x8*)&tr_lds[buf][((ntb + j) * 32 + l31) * ROWU + khalf * 8];
            acc[j] = __builtin_amdgcn_mfma_f32_32x32x16_bf16(a, b, acc[j], 0, 0, 0);
        }

        if (g + 1 < NG) {
#pragma unroll
            for (int q = 0; q < G; ++q) { pin0[q] = nin0[q]; pin1[q] = nin1[q]; pout[q] = nout_[q]; }
        }
    }

    // ---- epilogue: D[row, col] -> dw[o = mt*32+row, i = nt*32+col] ----
    float* base = dst + (size_t)(use_atomic ? (blockIdx.x % nslots) : blockIdx.x) * OUT_ELEMS;
#pragma unroll
    for (int j = 0; j < 4; ++j) {
        const int icol = (ntb + j) * 32 + l31;
#pragma unroll
        for (int r = 0; r < 16; ++r) {
            const int row = (r & 3) + 8 * (r >> 2) + 4 * khalf;
            const int o   = mt * 32 + row;
            const float v = acc[j][r];
            if (use_atomic) atomicAdd(&base[o * NIN + icol], v);
            else            base[o * NIN + icol] = v;
        }
    }
}

__global__ void zero_kernel(float* p, int n) {
    int i = blockIdx.x * blockDim.x + threadIdx.x;
    if (i < n) p[i] = 0.f;
}

__global__ __launch_bounds__(256)
void reduce_kernel(const float* __restrict__ ws, float* __restrict__ outp, int nslots) {
    const int idx = blockIdx.x * 256 + threadIdx.x;
    float s = 0.f;
    int k = 0;
    for (; k + 16 <= nslots; k += 16) {
        float v[16];
#pragma unroll
        for (int u = 0; u < 16; ++u) v[u] = ws[(size_t)(k + u) * OUT_ELEMS + idx];
#pragma unroll
        for (int u = 0; u < 16; ++u) s += v[u];
    }
    for (; k < nslots; ++k) s += ws[(size_t)k * OUT_ELEMS + idx];
    outp[idx] = s;
}

extern "C" void kernel_launch(void* const* d_in, const int* in_sizes, int n_in,
                              void* d_out, int out_size, void* d_ws, size_t ws_size,
                              hipStream_t stream) {
    const float* in   = (const float*)d_in[0];
    const float* outs = (const float*)d_in[1];
    float* out = (float*)d_out;
    float* ws  = (float*)d_ws;

    const size_t slot_bytes = (size_t)OUT_ELEMS * sizeof(float);

    if (ws_size >= (size_t)NBLOCKS * slot_bytes) {
        // plain per-block partials + reduce (preferred)
        stdp_main<<<NBLOCKS, 512, 0, stream>>>(in, outs, ws, NBLOCKS, 0);
        reduce_kernel<<<OUT_ELEMS / 256, 256, 0, stream>>>(ws, out, NBLOCKS);
    } else if (ws_size >= 16 * slot_bytes) {
        // 16 shared slots, atomic accumulation
        zero_kernel<<<(16 * OUT_ELEMS + 255) / 256, 256, 0, stream>>>(ws, 16 * OUT_ELEMS);
        stdp_main<<<NBLOCKS, 512, 0, stream>>>(in, outs, ws, 16, 1);
        reduce_kernel<<<OUT_ELEMS / 256, 256, 0, stream>>>(ws, out, 16);
    } else {
        // last resort: atomics straight into d_out
        zero_kernel<<<(OUT_ELEMS + 255) / 256, 256, 0, stream>>>(out, OUT_ELEMS);
        stdp_main<<<NBLOCKS, 512, 0, stream>>>(in, outs, out, 1, 1);
    }
}

// Round 2
// 450.899 us; speedup vs baseline: 1.0032x; 1.0032x over previous
//
#include <hip/hip_runtime.h>
#include <hip/hip_bf16.h>

// Problem constants (fixed by reference setup_inputs).
#define T_TOTAL 2048
#define BATCH   128
#define NIN     256
#define NOUT    128

// Decomposition: T-chunks x B-chunks. Warm-up recomputes trace history.
#define TC      256                 // timesteps per block
#define BC      4                   // batches per block
#define WARM    32                  // warm-up steps (0.5^32 ~ 2e-10 truncation)
#define G       4                   // timesteps per MFMA K-group (K = G*BC = 16)
#define NTC     (T_TOTAL / TC)      // 8
#define NBC     (BATCH / BC)        // 32
#define NBLOCKS (NTC * NBC)         // 256  (1 block/CU)
#define NG      (TC / G)            // 64 K-groups per block

#define ROWU      24                // ushorts per LDS row: 16 data + 8 pad = 48 B
#define OUT_ELEMS (NOUT * NIN)      // 32768

typedef __attribute__((ext_vector_type(8)))  __bf16 bf16x8;
typedef __attribute__((ext_vector_type(2)))  __bf16 bf16x2;
typedef __attribute__((ext_vector_type(16))) float  f32x16;

// packed f32x2 -> bf16x2 (v_cvt_pk_bf16_f32 on gfx950, RTNE)
static __device__ __forceinline__ unsigned pack_bf16(float a, float b) {
    bf16x2 v = { (__bf16)a, (__bf16)b };
    union { bf16x2 v; unsigned u; } c; c.v = v; return c.u;
}

// Main fused kernel: fp32 trace scan in registers + bf16 MFMA accumulation.
// 2-deep register prefetch pipeline: loads for group g issued at group g-2,
// so the s_waitcnt at consumption waits on ~2 group-times-old loads (slack
// >> HBM latency), decoupling the lock-step barrier from load delivery.
__global__ __launch_bounds__(512, 2)
void stdp_main(const float* __restrict__ in, const float* __restrict__ outs,
               float* __restrict__ dst, int nslots, int use_atomic)
{
    __shared__ unsigned short tr_lds[2][NIN * ROWU];   // 2 x 12 KB, B operand (trace, n=i)
    __shared__ unsigned short ot_lds[2][NOUT * ROWU];  // 2 x  6 KB, A operand (out-spikes, m=o)

    const int tid = threadIdx.x;
    const int bc  = blockIdx.x % NBC;
    const int tc  = blockIdx.x / NBC;
    const int b0  = bc * BC;
    const int t0  = tc * TC;

    // trace ownership: thread -> (i = tid&255, batches b0+2*bh, b0+2*bh+1)
    const int i_idx = tid & 255;
    const int bh    = tid >> 8;          // 0/1
    // out staging ownership: thread -> (o = tid&127, b_local = (tid>>7)&3)
    const int o_idx = tid & 127;
    const int blo   = (tid >> 7) & 3;

    float tr0 = 0.f, tr1 = 0.f;

    // ---- warm-up: trace scan only (no MFMA) ----
    if (tc > 0) {
        for (int t = t0 - WARM; t < t0; t += 8) {
            float v0[8], v1[8];
#pragma unroll
            for (int u = 0; u < 8; ++u) {
                const size_t base = ((size_t)(t + u) * BATCH + b0 + 2 * bh) * NIN + i_idx;
                v0[u] = in[base];
                v1[u] = in[base + NIN];
            }
#pragma unroll
            for (int u = 0; u < 8; ++u) {
                tr0 = 0.5f * tr0 + v0[u];
                tr1 = 0.5f * tr1 + v1[u];
            }
        }
    }

    f32x16 acc[4];
#pragma unroll
    for (int j = 0; j < 4; ++j) acc[j] = (f32x16)(0.f);

    const int lane  = tid & 63;
    const int wv    = tid >> 6;          // 8 waves
    const int mt    = wv & 3;            // m-tile (NOUT rows mt*32..+31)
    const int ntb   = (wv >> 2) * 4;     // n-tile base (4 tiles per wave)
    const int l31   = lane & 31;
    const int khalf = lane >> 5;         // 0/1 -> k offset 0/8

    // 2-stage register prefetch buffers
    float P0[2][G], P1[2][G], PO[2][G];

    auto load_stage = [&](int s, int g) {
        const int tg = t0 + g * G;
#pragma unroll
        for (int q = 0; q < G; ++q) {
            const size_t baseI = ((size_t)(tg + q) * BATCH + b0 + 2 * bh) * NIN + i_idx;
            P0[s][q] = in[baseI];
            P1[s][q] = in[baseI + NIN];
            PO[s][q] = outs[((size_t)(tg + q) * BATCH + b0 + blo) * NOUT + o_idx];
        }
    };

    auto body = [&](int s, int g) {
        // consume stage s: trace recurrence (exact fp32), packed bf16 cvt
        unsigned words[G];
        __bf16 ob[G];
#pragma unroll
        for (int q = 0; q < G; ++q) {
            tr0 = 0.5f * tr0 + P0[s][q];
            tr1 = 0.5f * tr1 + P1[s][q];
            words[q] = pack_bf16(tr0, tr1);
            ob[q] = (__bf16)PO[s][q];
        }
        // stage s is free: issue loads for group g+2 (2-deep pipeline)
        if (g + 2 < NG) load_stage(s, g + 2);

        // stage to LDS (double-buffered on s = g&1). k = q*BC + b_local
        unsigned* trow = (unsigned*)&tr_lds[s][i_idx * ROWU];
#pragma unroll
        for (int q = 0; q < G; ++q) trow[q * 2 + bh] = words[q];
        __bf16* orow = (__bf16*)&ot_lds[s][o_idx * ROWU];
#pragma unroll
        for (int q = 0; q < G; ++q) orow[q * 4 + blo] = ob[q];

        __syncthreads();   // single barrier per group

        // A frag: A[m = l31][k = khalf*8 + j]
        const bf16x8 a = *(const bf16x8*)&ot_lds[s][(mt * 32 + l31) * ROWU + khalf * 8];
#pragma unroll
        for (int j = 0; j < 4; ++j) {
            const bf16x8 b = *(const bf16x8*)&tr_lds[s][((ntb + j) * 32 + l31) * ROWU + khalf * 8];
            acc[j] = __builtin_amdgcn_mfma_f32_32x32x16_bf16(a, b, acc[j], 0, 0, 0);
        }
    };

    load_stage(0, 0);
    load_stage(1, 1);
    for (int gg = 0; gg < NG; gg += 2) {
        body(0, gg);
        body(1, gg + 1);
    }

    // ---- epilogue: D[row, col] -> dw[o = mt*32+row, i = nt*32+col] ----
    float* base = dst + (size_t)(use_atomic ? (blockIdx.x % nslots) : blockIdx.x) * OUT_ELEMS;
#pragma unroll
    for (int j = 0; j < 4; ++j) {
        const int icol = (ntb + j) * 32 + l31;
#pragma unroll
        for (int r = 0; r < 16; ++r) {
            const int row = (r & 3) + 8 * (r >> 2) + 4 * khalf;
            const int o   = mt * 32 + row;
            const float v = acc[j][r];
            if (use_atomic) atomicAdd(&base[o * NIN + icol], v);
            else            base[o * NIN + icol] = v;
        }
    }
}

__global__ void zero_kernel(float* p, int n) {
    int i = blockIdx.x * blockDim.x + threadIdx.x;
    if (i < n) p[i] = 0.f;
}

__global__ __launch_bounds__(256)
void reduce_kernel(const float* __restrict__ ws, float* __restrict__ outp, int nslots) {
    const int idx = blockIdx.x * 256 + threadIdx.x;
    float s = 0.f;
    int k = 0;
    for (; k + 16 <= nslots; k += 16) {
        float v[16];
#pragma unroll
        for (int u = 0; u < 16; ++u) v[u] = ws[(size_t)(k + u) * OUT_ELEMS + idx];
#pragma unroll
        for (int u = 0; u < 16; ++u) s += v[u];
    }
    for (; k < nslots; ++k) s += ws[(size_t)k * OUT_ELEMS + idx];
    outp[idx] = s;
}

extern "C" void kernel_launch(void* const* d_in, const int* in_sizes, int n_in,
                              void* d_out, int out_size, void* d_ws, size_t ws_size,
                              hipStream_t stream) {
    const float* in   = (const float*)d_in[0];
    const float* outs = (const float*)d_in[1];
    float* out = (float*)d_out;
    float* ws  = (float*)d_ws;

    const size_t slot_bytes = (size_t)OUT_ELEMS * sizeof(float);

    if (ws_size >= (size_t)NBLOCKS * slot_bytes) {
        // plain per-block partials + reduce (preferred)
        stdp_main<<<NBLOCKS, 512, 0, stream>>>(in, outs, ws, NBLOCKS, 0);
        reduce_kernel<<<OUT_ELEMS / 256, 256, 0, stream>>>(ws, out, NBLOCKS);
    } else if (ws_size >= 16 * slot_bytes) {
        // 16 shared slots, atomic accumulation
        zero_kernel<<<(16 * OUT_ELEMS + 255) / 256, 256, 0, stream>>>(ws, 16 * OUT_ELEMS);
        stdp_main<<<NBLOCKS, 512, 0, stream>>>(in, outs, ws, 16, 1);
        reduce_kernel<<<OUT_ELEMS / 256, 256, 0, stream>>>(ws, out, 16);
    } else {
        // last resort: atomics straight into d_out
        zero_kernel<<<(OUT_ELEMS + 255) / 256, 256, 0, stream>>>(out, OUT_ELEMS);
        stdp_main<<<NBLOCKS, 512, 0, stream>>>(in, outs, out, 1, 1);
    }
}